// Round 5
// baseline (244.962 us; speedup 1.0000x reference)
//
#include <hip/hip_runtime.h>

typedef __bf16 bf16_t;
typedef __bf16 bf16x8 __attribute__((ext_vector_type(8)));
typedef __bf16 bf16x4v __attribute__((ext_vector_type(4)));
typedef float f32x4 __attribute__((ext_vector_type(4)));

#define KN 50
#define B_TOT 16384
#define NITER 32
#define NBLK (B_TOT / NITER)

// packed weight layout in d_ws (bf16 elems), [n][k] transposed:
// W1: [64][104] (k<72 data, rest 0)   off 0
// W2: [64][72]  (k<64 data)           off 6656
// A1: [64][136] (k<128 data)          off 11264   (main kernel reads k<64 only)
// A2: [64][72]  (k<64 data)           off 19968
#define W1_OFF 0
#define W1_STR 104
#define W2_OFF 6656
#define W2_STR 72
#define A1_OFF 11264
#define A1_STR 136
#define A2_OFF 19968
#define A2_STR 72
#define W_ELEMS 24576
#define BIAS_BYTE_OFF (W_ELEMS * 2)
#define PACK_TOT (W_ELEMS + 321)
#define CU_BYTE_OFF 65536   // c_u[B_TOT][64] bf16 (2 MB)

__global__ __launch_bounds__(256) void pack_weights_k(
    const float* __restrict__ w1, const float* __restrict__ w2,
    const float* __restrict__ a1, const float* __restrict__ a2,
    const float* __restrict__ b1, const float* __restrict__ b2,
    const float* __restrict__ ab1, const float* __restrict__ ab2,
    const float* __restrict__ a3w, const float* __restrict__ a3b,
    void* __restrict__ ws)
{
  int idx = blockIdx.x * 256 + threadIdx.x;
  if (idx >= PACK_TOT) return;
  bf16_t* wp = (bf16_t*)ws;
  float* bp = (float*)((char*)ws + BIAS_BYTE_OFF);
  if (idx < W2_OFF) {
    int n = idx / W1_STR, k = idx % W1_STR;
    wp[idx] = (bf16_t)((k < 72) ? w1[k * 64 + n] : 0.f);
  } else if (idx < A1_OFF) {
    int e = idx - W2_OFF; int n = e / W2_STR, k = e % W2_STR;
    wp[idx] = (bf16_t)((k < 64) ? w2[k * 64 + n] : 0.f);
  } else if (idx < A2_OFF) {
    int e = idx - A1_OFF; int n = e / A1_STR, k = e % A1_STR;
    wp[idx] = (bf16_t)((k < 128) ? a1[k * 64 + n] : 0.f);
  } else if (idx < W_ELEMS) {
    int e = idx - A2_OFF; int n = e / A2_STR, k = e % A2_STR;
    wp[idx] = (bf16_t)((k < 64) ? a2[k * 64 + n] : 0.f);
  } else {
    int e = idx - W_ELEMS;
    float v;
    if (e < 64) v = b1[e];
    else if (e < 128) v = b2[e - 64];
    else if (e < 192) v = ab1[e - 128];
    else if (e < 256) v = ab2[e - 192];
    else if (e < 320) v = a3w[e - 256];
    else v = a3b[0];
    bp[e] = v;
  }
}

// c_u[b][f] = sum_j u2e[nodes[b]][j] * a1W[64+j][f] + a1b[f]   (fp32 math, bf16 store)
__global__ __launch_bounds__(256) void cu_prep_k(
    const int* __restrict__ nodes, const float* __restrict__ u2e,
    const float* __restrict__ a1W, const float* __restrict__ a1b,
    void* __restrict__ ws)
{
  const int t = blockIdx.x * 256 + threadIdx.x;
  const int bi = t >> 6;      // node index 0..16383 (wave-uniform)
  const int f  = t & 63;
  bf16_t* cu = (bf16_t*)((char*)ws + CU_BYTE_OFF);
  const int nd = nodes[bi];
  const float* ur = u2e + (size_t)nd * 64;
  float s = a1b[f];
#pragma unroll
  for (int j = 0; j < 64; ++j) s += ur[j] * a1W[(64 + j) * 64 + f];
  cu[(size_t)bi * 64 + f] = (bf16_t)s;
}

__device__ __forceinline__ bf16x8 cvt8(float4 a, float4 b) {
  bf16x8 r;
  r[0] = (bf16_t)a.x; r[1] = (bf16_t)a.y; r[2] = (bf16_t)a.z; r[3] = (bf16_t)a.w;
  r[4] = (bf16_t)b.x; r[5] = (bf16_t)b.y; r[6] = (bf16_t)b.z; r[7] = (bf16_t)b.w;
  return r;
}

__device__ __forceinline__ float4 ldf4(const float* p) {
  return *reinterpret_cast<const float4*>(p);
}

// wave w: mh = w>>1 (neighbor half: rows mh*32 + nt*16 + lrow, nt=0,1)
//         nh = w&1  (feature half: feats nh*32 + ft*16 + lg*4+r, ft=0,1)
// MFMA: A = weight frag (m=feat_out), B = activation frag (n=neighbor)
// D layout: lane holds D[feat = lg*4+r][neighbor = lrow]  -> packed b64 writes
__global__ __launch_bounds__(256, 2) void social_agg_k(
    const int* __restrict__ nodes,
    const int* __restrict__ nidx,
    const int* __restrict__ nlen,
    const float* __restrict__ labels,
    const float* __restrict__ u2e,
    const void* __restrict__ wsv,
    float* __restrict__ out)
{
  __shared__ __align__(16) bf16_t Hs[64][72];   // stage1 out / stage3 out
  __shared__ __align__(16) bf16_t Os[64][72];   // o_history bf16
  __shared__ float scp[2][64];                  // per-nh partial scores
  __shared__ float part[2][64];                 // per-mh partial aggregates

  const bf16_t* wp = (const bf16_t*)wsv;
  const float*  bp = (const float*)((const char*)wsv + BIAS_BYTE_OFF);
  const bf16_t* cu = (const bf16_t*)((const char*)wsv + CU_BYTE_OFF);

  const int tid  = threadIdx.x;
  const int lane = tid & 63;
  const int w    = tid >> 6;
  const int mh   = w >> 1;
  const int nh   = w & 1;
  const int lrow = lane & 15;
  const int lg   = lane >> 4;

  // ---- weight fragments -> registers (A-operand layout == old B layout) ----
  bf16x8 w1f[2][3], w2f[2][2], a1f[2][2], a2f[2][2];
#pragma unroll
  for (int ft = 0; ft < 2; ++ft) {
    const int n0 = (nh * 32 + ft * 16 + lrow);
#pragma unroll
    for (int s = 0; s < 3; ++s)
      w1f[ft][s] = *reinterpret_cast<const bf16x8*>(wp + W1_OFF + n0 * W1_STR + s * 32 + lg * 8);
#pragma unroll
    for (int s = 0; s < 2; ++s) {
      w2f[ft][s] = *reinterpret_cast<const bf16x8*>(wp + W2_OFF + n0 * W2_STR + s * 32 + lg * 8);
      a1f[ft][s] = *reinterpret_cast<const bf16x8*>(wp + A1_OFF + n0 * A1_STR + s * 32 + lg * 8);
      a2f[ft][s] = *reinterpret_cast<const bf16x8*>(wp + A2_OFF + n0 * A2_STR + s * 32 + lg * 8);
    }
  }

  // ---- biases as f32x4 per (stage, ft); feat = nh*32+ft*16+lg*4+r ----
  f32x4 bb1[2], bb2[2], ba2[2], a3c4[2];
#pragma unroll
  for (int ft = 0; ft < 2; ++ft) {
    const int fb = nh * 32 + ft * 16 + lg * 4;
    bb1[ft]  = *reinterpret_cast<const f32x4*>(bp + fb);
    bb2[ft]  = *reinterpret_cast<const f32x4*>(bp + 64 + fb);
    ba2[ft]  = *reinterpret_cast<const f32x4*>(bp + 192 + fb);
    a3c4[ft] = *reinterpret_cast<const f32x4*>(bp + 256 + fb);
  }

  const int b0 = blockIdx.x * NITER;
  int crow[2];
#pragma unroll
  for (int nt = 0; nt < 2; ++nt) {
    const int nb = mh * 32 + nt * 16 + lrow;
    crow[nt] = (nb < KN) ? nb : (KN - 1);
  }

  // ---- prologue prefetch ----
  int giC[2], giN[2];
  float4 px[2][4];
  float4 plb[2][2] = {{{0,0,0,0},{0,0,0,0}},{{0,0,0,0},{0,0,0,0}}};
  bf16x4v pcu[2];
  int ndC = nodes[b0];
  int lnC = nlen[b0];
#pragma unroll
  for (int nt = 0; nt < 2; ++nt) {
    giC[nt] = nidx[(size_t)b0 * KN + crow[nt]];
    const float* xr = u2e + (size_t)giC[nt] * 64;
    px[nt][0] = ldf4(xr + lg * 8);
    px[nt][1] = ldf4(xr + lg * 8 + 4);
    px[nt][2] = ldf4(xr + 32 + lg * 8);
    px[nt][3] = ldf4(xr + 32 + lg * 8 + 4);
    if (lg == 0) {
      const float* lb = labels + ((size_t)b0 * KN + crow[nt]) * 8;
      plb[nt][0] = ldf4(lb); plb[nt][1] = ldf4(lb + 4);
    }
  }
#pragma unroll
  for (int ft = 0; ft < 2; ++ft)
    pcu[ft] = *reinterpret_cast<const bf16x4v*>(cu + (size_t)b0 * 64 + nh * 32 + ft * 16 + lg * 4);
  int ndN = nodes[b0 + 1];
  int lnN = nlen[b0 + 1];
#pragma unroll
  for (int nt = 0; nt < 2; ++nt)
    giN[nt] = nidx[(size_t)(b0 + 1) * KN + crow[nt]];

  for (int it = 0; it < NITER; ++it) {
    const int b = b0 + it;

    // ---- convert current prefetched data (waits on in-flight loads) ----
    bf16x8 xa[2][3];
    f32x4 cu4[2];
#pragma unroll
    for (int nt = 0; nt < 2; ++nt) {
      xa[nt][0] = cvt8(px[nt][0], px[nt][1]);
      xa[nt][1] = cvt8(px[nt][2], px[nt][3]);
      xa[nt][2] = cvt8(plb[nt][0], plb[nt][1]);   // zeros for lg!=0
    }
#pragma unroll
    for (int ft = 0; ft < 2; ++ft) {
#pragma unroll
      for (int r = 0; r < 4; ++r) cu4[ft][r] = (float)pcu[ft][r];
    }
    const int lenCur = lnC;
    const int ndCur  = ndC;

    // ---- issue next node's loads ----
    if (it + 1 < NITER) {
#pragma unroll
      for (int nt = 0; nt < 2; ++nt) {
        const float* xr2 = u2e + (size_t)giN[nt] * 64;
        px[nt][0] = ldf4(xr2 + lg * 8);
        px[nt][1] = ldf4(xr2 + lg * 8 + 4);
        px[nt][2] = ldf4(xr2 + 32 + lg * 8);
        px[nt][3] = ldf4(xr2 + 32 + lg * 8 + 4);
        if (lg == 0) {
          const float* lb2 = labels + ((size_t)(b + 1) * KN + crow[nt]) * 8;
          plb[nt][0] = ldf4(lb2); plb[nt][1] = ldf4(lb2 + 4);
        }
      }
#pragma unroll
      for (int ft = 0; ft < 2; ++ft)
        pcu[ft] = *reinterpret_cast<const bf16x4v*>(cu + (size_t)(b + 1) * 64 + nh * 32 + ft * 16 + lg * 4);
      lnC = lnN; ndC = ndN;
      const int b2 = (it + 2 < NITER) ? (b + 2) : b;
#pragma unroll
      for (int nt = 0; nt < 2; ++nt)
        giN[nt] = nidx[(size_t)b2 * KN + crow[nt]];
      ndN = nodes[b2];
      lnN = nlen[b2];
    }

    f32x4 acc[2][2];

    // ========== stage 1: H = relu(X @ W1 + b1), K=96 ==========
#pragma unroll
    for (int nt = 0; nt < 2; ++nt)
#pragma unroll
      for (int ft = 0; ft < 2; ++ft) acc[nt][ft] = bb1[ft];
#pragma unroll
    for (int s = 0; s < 3; ++s)
#pragma unroll
      for (int nt = 0; nt < 2; ++nt)
#pragma unroll
        for (int ft = 0; ft < 2; ++ft)
          acc[nt][ft] = __builtin_amdgcn_mfma_f32_16x16x32_bf16(w1f[ft][s], xa[nt][s], acc[nt][ft], 0, 0, 0);
#pragma unroll
    for (int nt = 0; nt < 2; ++nt)
#pragma unroll
      for (int ft = 0; ft < 2; ++ft) {
        bf16x4v h;
#pragma unroll
        for (int r = 0; r < 4; ++r) { float v = acc[nt][ft][r]; h[r] = (bf16_t)(v > 0.f ? v : 0.f); }
        *reinterpret_cast<bf16x4v*>(&Hs[mh * 32 + nt * 16 + lrow][nh * 32 + ft * 16 + lg * 4]) = h;
      }
    __syncthreads();

    // ========== stage 2: O = relu(H @ W2 + b2), K=64 ==========
#pragma unroll
    for (int nt = 0; nt < 2; ++nt)
#pragma unroll
      for (int ft = 0; ft < 2; ++ft) acc[nt][ft] = bb2[ft];
#pragma unroll
    for (int s = 0; s < 2; ++s)
#pragma unroll
      for (int nt = 0; nt < 2; ++nt) {
        bf16x8 hb = *reinterpret_cast<const bf16x8*>(&Hs[mh * 32 + nt * 16 + lrow][s * 32 + lg * 8]);
#pragma unroll
        for (int ft = 0; ft < 2; ++ft)
          acc[nt][ft] = __builtin_amdgcn_mfma_f32_16x16x32_bf16(w2f[ft][s], hb, acc[nt][ft], 0, 0, 0);
      }
    f32x4 osv[2][2];
#pragma unroll
    for (int nt = 0; nt < 2; ++nt)
#pragma unroll
      for (int ft = 0; ft < 2; ++ft) {
        bf16x4v h;
#pragma unroll
        for (int r = 0; r < 4; ++r) {
          float v = acc[nt][ft][r]; v = v > 0.f ? v : 0.f;
          osv[nt][ft][r] = v; h[r] = (bf16_t)v;
        }
        *reinterpret_cast<bf16x4v*>(&Os[mh * 32 + nt * 16 + lrow][nh * 32 + ft * 16 + lg * 4]) = h;
      }
    __syncthreads();

    // ========== stage 3: A1 = relu(O @ a1W[0:64] + c_u), K=64 ==========
#pragma unroll
    for (int nt = 0; nt < 2; ++nt)
#pragma unroll
      for (int ft = 0; ft < 2; ++ft) acc[nt][ft] = cu4[ft];
#pragma unroll
    for (int s = 0; s < 2; ++s)
#pragma unroll
      for (int nt = 0; nt < 2; ++nt) {
        bf16x8 ob = *reinterpret_cast<const bf16x8*>(&Os[mh * 32 + nt * 16 + lrow][s * 32 + lg * 8]);
#pragma unroll
        for (int ft = 0; ft < 2; ++ft)
          acc[nt][ft] = __builtin_amdgcn_mfma_f32_16x16x32_bf16(a1f[ft][s], ob, acc[nt][ft], 0, 0, 0);
      }
#pragma unroll
    for (int nt = 0; nt < 2; ++nt)
#pragma unroll
      for (int ft = 0; ft < 2; ++ft) {
        bf16x4v h;
#pragma unroll
        for (int r = 0; r < 4; ++r) { float v = acc[nt][ft][r]; h[r] = (bf16_t)(v > 0.f ? v : 0.f); }
        *reinterpret_cast<bf16x4v*>(&Hs[mh * 32 + nt * 16 + lrow][nh * 32 + ft * 16 + lg * 4]) = h;
      }
    __syncthreads();

    // ===== stage 4: A2 = relu(A1 @ a2W + a2b); scores = A2 @ a3 (a3b cancels) =====
#pragma unroll
    for (int nt = 0; nt < 2; ++nt)
#pragma unroll
      for (int ft = 0; ft < 2; ++ft) acc[nt][ft] = ba2[ft];
#pragma unroll
    for (int s = 0; s < 2; ++s)
#pragma unroll
      for (int nt = 0; nt < 2; ++nt) {
        bf16x8 hb = *reinterpret_cast<const bf16x8*>(&Hs[mh * 32 + nt * 16 + lrow][s * 32 + lg * 8]);
#pragma unroll
        for (int ft = 0; ft < 2; ++ft)
          acc[nt][ft] = __builtin_amdgcn_mfma_f32_16x16x32_bf16(a2f[ft][s], hb, acc[nt][ft], 0, 0, 0);
      }
    {
      float sc[2] = {0.f, 0.f};
#pragma unroll
      for (int nt = 0; nt < 2; ++nt)
#pragma unroll
        for (int ft = 0; ft < 2; ++ft)
#pragma unroll
          for (int r = 0; r < 4; ++r) {
            float v = acc[nt][ft][r]; v = v > 0.f ? v : 0.f;
            sc[nt] += v * a3c4[ft][r];
          }
#pragma unroll
      for (int nt = 0; nt < 2; ++nt) {
        sc[nt] += __shfl_xor(sc[nt], 16, 64);
        sc[nt] += __shfl_xor(sc[nt], 32, 64);
      }
      if (lg == 0) {
#pragma unroll
        for (int nt = 0; nt < 2; ++nt)
          scp[nh][mh * 32 + nt * 16 + lrow] = sc[nt];
      }
    }
    __syncthreads();

    // ===== masked softmax, redundantly per wave =====
    float att4[2];
    {
      const bool valid = lane < lenCur;
      float s = valid ? (scp[0][lane] + scp[1][lane]) : -1e30f;
      float m = s;
#pragma unroll
      for (int k = 1; k < 64; k <<= 1) m = fmaxf(m, __shfl_xor(m, k, 64));
      float e = valid ? __expf(s - m) : 0.f;
      float sm = e;
#pragma unroll
      for (int k = 1; k < 64; k <<= 1) sm += __shfl_xor(sm, k, 64);
      float att_own = (sm > 0.f) ? e / sm : 0.f;
#pragma unroll
      for (int nt = 0; nt < 2; ++nt)
        att4[nt] = __shfl(att_own, mh * 32 + nt * 16 + lrow, 64);
    }

    // ===== aggregate: agg[feat] = sum_nb att[nb]*O[nb][feat], fp32 regs =====
#pragma unroll
    for (int ft = 0; ft < 2; ++ft) {
      float pr[4];
#pragma unroll
      for (int r = 0; r < 4; ++r)
        pr[r] = att4[0] * osv[0][ft][r] + att4[1] * osv[1][ft][r];
#pragma unroll
      for (int r = 0; r < 4; ++r) {
#pragma unroll
        for (int m = 1; m < 16; m <<= 1) pr[r] += __shfl_xor(pr[r], m, 64);
      }
      if (lrow == 0) {
        float4 pv = {pr[0], pr[1], pr[2], pr[3]};
        *reinterpret_cast<float4*>(&part[mh][nh * 32 + ft * 16 + lg * 4]) = pv;
      }
    }
    __syncthreads();
    if (tid < 64) {
      float v = part[0][tid] + part[1][tid];
      out[(size_t)b * 64 + tid] = (lenCur > 0) ? v : u2e[(size_t)ndCur * 64 + tid];
    }
  }
}

extern "C" void kernel_launch(void* const* d_in, const int* in_sizes, int n_in,
                              void* d_out, int out_size, void* d_ws, size_t ws_size,
                              hipStream_t stream) {
  (void)in_sizes; (void)n_in; (void)out_size; (void)ws_size;
  const int*   nodes  = (const int*)d_in[0];
  const int*   nidx   = (const int*)d_in[1];
  const int*   nlen   = (const int*)d_in[2];
  const float* labels = (const float*)d_in[3];
  const float* u2e    = (const float*)d_in[4];
  const float* w1W    = (const float*)d_in[5];
  const float* w1b    = (const float*)d_in[6];
  const float* w2W    = (const float*)d_in[7];
  const float* w2b    = (const float*)d_in[8];
  const float* a1W    = (const float*)d_in[9];
  const float* a1b    = (const float*)d_in[10];
  const float* a2W    = (const float*)d_in[11];
  const float* a2b    = (const float*)d_in[12];
  const float* a3W    = (const float*)d_in[13];
  const float* a3b    = (const float*)d_in[14];
  float* out = (float*)d_out;

  pack_weights_k<<<(PACK_TOT + 255) / 256, 256, 0, stream>>>(
      w1W, w2W, a1W, a2W, w1b, w2b, a1b, a2b, a3W, a3b, d_ws);
  cu_prep_k<<<(B_TOT * 64) / 256, 256, 0, stream>>>(nodes, u2e, a1W, a1b, d_ws);
  social_agg_k<<<NBLK, 256, 0, stream>>>(nodes, nidx, nlen, labels, u2e, d_ws, out);
}